// Round 1
// baseline (382.427 us; speedup 1.0000x reference)
//
#include <hip/hip_runtime.h>
#include <hip/hip_bf16.h>
#include <stdint.h>
#include <stddef.h>

typedef __bf16 bf16_t;
typedef __bf16 bf16x8 __attribute__((ext_vector_type(8)));
typedef float  f32x4  __attribute__((ext_vector_type(4)));

#define NN 1024
#define H  128

// ---------------- We fp32 -> bf16 ----------------
__global__ void k_cvt_we(const float* __restrict__ src, bf16_t* __restrict__ dst) {
    int i = blockIdx.x * 256 + threadIdx.x;
    if (i < H * H) dst[i] = (bf16_t)src[i];
}

// ---------------- f_i = node @ Wi^T, f_j = node @ Wj^T (fp32 compute, bf16 store) ----------------
__global__ void k_proj(const float* __restrict__ node,
                       const float* __restrict__ Wi,
                       const float* __restrict__ Wj,
                       bf16_t* __restrict__ fi,
                       bf16_t* __restrict__ fj) {
    __shared__ float nrow[H];
    const int row = blockIdx.x;       // 0..1023
    const int t   = threadIdx.x;      // 0..255
    const int h   = t & (H - 1);
    const int sel = t >> 7;           // 0 -> f_i, 1 -> f_j
    if (t < H) nrow[t] = node[(size_t)row * H + t];
    __syncthreads();
    const float* w = (sel ? Wj : Wi) + (size_t)h * H;
    float acc = 0.f;
    #pragma unroll
    for (int k4 = 0; k4 < H / 4; ++k4) {
        f32x4 wv = *(const f32x4*)(w + k4 * 4);
        f32x4 nv = *(const f32x4*)(&nrow[k4 * 4]);
        acc += nv[0] * wv[0] + nv[1] * wv[1] + nv[2] * wv[2] + nv[3] * wv[3];
    }
    bf16_t* dst = sel ? fj : fi;
    dst[(size_t)row * H + h] = (bf16_t)acc;
}

// ---------------- dots[i][j] = f_i[i] . f_j[j]  (bf16 MFMA, fp32 out) ----------------
// grid = 64 blocks: 8x8 tiles of 128x128; block = 256 thr (4 waves, 32 rows each)
__global__ __launch_bounds__(256, 4)
void k_dots(const bf16_t* __restrict__ fi,
            const bf16_t* __restrict__ fj,
            float* __restrict__ dots) {
    const int t    = threadIdx.x;
    const int wave = t >> 6;
    const int lane = t & 63;
    const int l15  = lane & 15;
    const int g    = lane >> 4;

    const int bm    = blockIdx.x >> 3;
    const int bn    = blockIdx.x & 7;
    const int ibase = bm * 128 + wave * 32;
    const int jbase = bn * 128;

    f32x4 acc[2][8];
    #pragma unroll
    for (int mf = 0; mf < 2; ++mf)
        #pragma unroll
        for (int nt = 0; nt < 8; ++nt)
            acc[mf][nt] = (f32x4){0.f, 0.f, 0.f, 0.f};

    const bf16_t* a0 = fi + (size_t)(ibase +  0 + l15) * H + g * 8;
    const bf16_t* a1 = fi + (size_t)(ibase + 16 + l15) * H + g * 8;

    #pragma unroll
    for (int kst = 0; kst < 4; ++kst) {
        bf16x8 af0 = *(const bf16x8*)(a0 + kst * 32);
        bf16x8 af1 = *(const bf16x8*)(a1 + kst * 32);
        #pragma unroll
        for (int nt = 0; nt < 8; ++nt) {
            bf16x8 bf = *(const bf16x8*)(fj + (size_t)(jbase + nt * 16 + l15) * H + kst * 32 + g * 8);
            acc[0][nt] = __builtin_amdgcn_mfma_f32_16x16x32_bf16(af0, bf, acc[0][nt], 0, 0, 0);
            acc[1][nt] = __builtin_amdgcn_mfma_f32_16x16x32_bf16(af1, bf, acc[1][nt], 0, 0, 0);
        }
    }

    #pragma unroll
    for (int mf = 0; mf < 2; ++mf) {
        const int rbase = ibase + mf * 16 + g * 4;
        #pragma unroll
        for (int r = 0; r < 4; ++r) {
            #pragma unroll
            for (int nt = 0; nt < 8; ++nt)
                dots[(size_t)(rbase + r) * NN + jbase + nt * 16 + l15] = acc[mf][nt][r];
        }
    }
}

// ---------------- main: out = relu(edge @ We^T + be + dots[e]) ----------------
// grid = 8192 blocks x 256 thr; block covers 128 rows (wave w: rows [128b + 32w, +32))
__global__ __launch_bounds__(256, 4)
void k_main(const float* __restrict__ edge,   // [1M][128] fp32
            const bf16_t* __restrict__ web,   // [128][128] bf16 (row h, col k)
            const float* __restrict__ be,     // [128]
            const float* __restrict__ dots,   // [1M]
            float* __restrict__ out) {        // [1M][128] fp32
    const int t    = threadIdx.x;
    const int wave = t >> 6;
    const int lane = t & 63;
    const int l15  = lane & 15;
    const int g    = lane >> 4;

    const size_t mbase = (size_t)blockIdx.x * 128 + wave * 32;

    f32x4 acc[2][8];
    #pragma unroll
    for (int mf = 0; mf < 2; ++mf)
        #pragma unroll
        for (int nt = 0; nt < 8; ++nt)
            acc[mf][nt] = (f32x4){0.f, 0.f, 0.f, 0.f};

    const float* arow0 = edge + (mbase +  0 + l15) * H + g * 8;
    const float* arow1 = edge + (mbase + 16 + l15) * H + g * 8;

    #pragma unroll
    for (int kst = 0; kst < 4; ++kst) {
        f32x4 u0 = *(const f32x4*)(arow0 + kst * 32);
        f32x4 u1 = *(const f32x4*)(arow0 + kst * 32 + 4);
        f32x4 u2 = *(const f32x4*)(arow1 + kst * 32);
        f32x4 u3 = *(const f32x4*)(arow1 + kst * 32 + 4);
        bf16x8 af0, af1;
        #pragma unroll
        for (int i = 0; i < 4; ++i) {
            af0[i]     = (bf16_t)u0[i];
            af0[i + 4] = (bf16_t)u1[i];
            af1[i]     = (bf16_t)u2[i];
            af1[i + 4] = (bf16_t)u3[i];
        }
        #pragma unroll
        for (int nt = 0; nt < 8; ++nt) {
            bf16x8 bf = *(const bf16x8*)(web + (size_t)(nt * 16 + l15) * H + kst * 32 + g * 8);
            acc[0][nt] = __builtin_amdgcn_mfma_f32_16x16x32_bf16(af0, bf, acc[0][nt], 0, 0, 0);
            acc[1][nt] = __builtin_amdgcn_mfma_f32_16x16x32_bf16(af1, bf, acc[1][nt], 0, 0, 0);
        }
    }

    float bias[8];
    #pragma unroll
    for (int nt = 0; nt < 8; ++nt) bias[nt] = be[nt * 16 + l15];

    float dv[2][4];
    #pragma unroll
    for (int mf = 0; mf < 2; ++mf)
        #pragma unroll
        for (int r = 0; r < 4; ++r)
            dv[mf][r] = dots[mbase + mf * 16 + g * 4 + r];

    #pragma unroll
    for (int mf = 0; mf < 2; ++mf) {
        const size_t rbase = mbase + mf * 16 + g * 4;
        #pragma unroll
        for (int r = 0; r < 4; ++r) {
            const size_t orow = (rbase + r) * H;
            #pragma unroll
            for (int nt = 0; nt < 8; ++nt) {
                float v = acc[mf][nt][r] + bias[nt] + dv[mf][r];
                out[orow + nt * 16 + l15] = fmaxf(v, 0.f);
            }
        }
    }
}

extern "C" void kernel_launch(void* const* d_in, const int* in_sizes, int n_in,
                              void* d_out, int out_size, void* d_ws, size_t ws_size,
                              hipStream_t stream) {
    const float* node = (const float*)d_in[0];
    const float* edge = (const float*)d_in[1];
    const float* We   = (const float*)d_in[2];
    const float* be   = (const float*)d_in[3];
    const float* Wi   = (const float*)d_in[4];
    const float* Wj   = (const float*)d_in[5];
    float* out = (float*)d_out;

    char* w = (char*)d_ws;
    bf16_t* fi_bf = (bf16_t*)w;                              // 256 KB
    bf16_t* fj_bf = (bf16_t*)(w + (256 << 10));              // 256 KB
    float*  dots  = (float*)(w + (512 << 10));               // 4 MB
    bf16_t* web   = (bf16_t*)(w + (512 << 10) + (4 << 20));  // 32 KB

    k_cvt_we<<<(H * H + 255) / 256, 256, 0, stream>>>(We, web);
    k_proj<<<NN, 256, 0, stream>>>(node, Wi, Wj, fi_bf, fj_bf);
    k_dots<<<64, 256, 0, stream>>>(fi_bf, fj_bf, dots);
    k_main<<<(NN * NN) / 128, 256, 0, stream>>>(edge, web, be, dots, out);
}